// Round 2
// baseline (1071.189 us; speedup 1.0000x reference)
//
#include <hip/hip_runtime.h>
#include <hip/hip_bf16.h>

#define BB 16
#define NN 4096
#define SS 1024
#define DD 256
#define O1 256
#define O2 128

// ---------------------------------------------------------------------------
// Kernel A: 3-nearest-neighbor search + inverse-distance weights
// grid: BB * (NN/256) blocks, 256 threads. One thread per (b, n).
// ---------------------------------------------------------------------------
__global__ __launch_bounds__(256) void knn3_kernel(
    const float* __restrict__ xyz1,   // [B,3,N]
    const float* __restrict__ xyz2,   // [B,3,S]
    int* __restrict__ idx_out,        // [B,N,3]
    float* __restrict__ w_out)        // [B,N,3]
{
    __shared__ float4 q[SS];          // {x, y, z, |p|^2} of xyz2 points (16 KB)

    const int b    = blockIdx.x >> 4;        // 16 tiles per batch
    const int tile = blockIdx.x & 15;
    const int n    = tile * 256 + threadIdx.x;

    const float* x2 = xyz2 + (size_t)b * 3 * SS;
    for (int s = threadIdx.x; s < SS; s += 256) {
        float xx = x2[s];
        float yy = x2[SS + s];
        float zz = x2[2 * SS + s];
        q[s] = make_float4(xx, yy, zz, xx * xx + yy * yy + zz * zz);
    }
    __syncthreads();

    const float* x1 = xyz1 + (size_t)b * 3 * NN;
    const float px = x1[n];
    const float py = x1[NN + n];
    const float pz = x1[2 * NN + n];
    const float pn = px * px + py * py + pz * pz;

    const float FINF = 3.402823466e+38f;
    float d0 = FINF, d1 = FINF, d2 = FINF;
    int   i0 = 0,    i1 = 0,    i2 = 0;

    #pragma unroll 4
    for (int s = 0; s < SS; ++s) {
        float4 v = q[s];
        float dot = px * v.x + py * v.y + pz * v.z;
        // same algebraic form & association as the reference:
        // (|x1|^2 + |x2|^2) - 2*dot
        float d = pn + v.w - 2.0f * dot;
        if (d < d2) {
            if (d < d1) {
                if (d < d0) { d2 = d1; i2 = i1; d1 = d0; i1 = i0; d0 = d; i0 = s; }
                else        { d2 = d1; i2 = i1; d1 = d;  i1 = s; }
            } else          { d2 = d;  i2 = s; }
        }
    }

    float r0 = 1.0f / (d0 + 1e-8f);
    float r1 = 1.0f / (d1 + 1e-8f);
    float r2 = 1.0f / (d2 + 1e-8f);
    float rs = 1.0f / (r0 + r1 + r2);

    size_t base = ((size_t)b * NN + n) * 3;
    idx_out[base + 0] = i0;
    idx_out[base + 1] = i1;
    idx_out[base + 2] = i2;
    w_out[base + 0] = r0 * rs;
    w_out[base + 1] = r1 * rs;
    w_out[base + 2] = r2 * rs;
}

// ---------------------------------------------------------------------------
// Kernel B: fused gather-interp + (conv1x1 + BN + ReLU) x 2
// grid: BB * (NN/64) = 1024 blocks, 256 threads (4 waves).
// Tile: 64 points. LDS: x[256][64] fp32 = 64 KB, reused for y1 after layer 1.
// Each wave owns 64 output rows of layer 1 (32 rows of layer 2); W reads are
// wave-uniform -> scalar loads.
// ---------------------------------------------------------------------------
__global__ __launch_bounds__(256, 2) void fused_interp_mlp_kernel(
    const float* __restrict__ points1,  // [B,D,N]
    const float* __restrict__ points2,  // [B,D,S]
    const int*   __restrict__ idx_in,   // [B,N,3]
    const float* __restrict__ w_in,     // [B,N,3]
    const float* __restrict__ W1, const float* __restrict__ b1,
    const float* __restrict__ g1, const float* __restrict__ be1,
    const float* __restrict__ m1, const float* __restrict__ v1,
    const float* __restrict__ W2, const float* __restrict__ b2,
    const float* __restrict__ g2, const float* __restrict__ be2,
    const float* __restrict__ m2, const float* __restrict__ v2,
    float* __restrict__ out)            // [B,O2,N]
{
    __shared__ float xls[DD * 64];      // 64 KB: x[c][p], later y1[o][p]

    const int blk  = blockIdx.x;
    const int b    = blk >> 6;          // 64 tiles per batch
    const int n0   = (blk & 63) << 6;
    const int tid  = threadIdx.x;
    const int p    = tid & 63;          // point within tile == lane
    const int cg   = tid >> 6;          // 0..3 (c-group == wave id)
    const int n    = n0 + p;

    // per-point interpolation metadata (same for all c this thread touches)
    const size_t ibase = ((size_t)b * NN + n) * 3;
    const int   i0 = idx_in[ibase + 0];
    const int   i1 = idx_in[ibase + 1];
    const int   i2 = idx_in[ibase + 2];
    const float w0 = w_in[ibase + 0];
    const float w1v = w_in[ibase + 1];
    const float w2v = w_in[ibase + 2];

    const float* p1 = points1 + (size_t)b * DD * NN + n;
    const float* p2 = points2 + (size_t)b * DD * SS;

    // stage x[c][p] = points1[b,c,n] + sum_k w_k * points2[b,c,idx_k]
    #pragma unroll 2
    for (int c = cg; c < DD; c += 4) {
        const float* row = p2 + (size_t)c * SS;
        float val = p1[(size_t)c * NN]
                  + w0 * row[i0] + w1v * row[i1] + w2v * row[i2];
        xls[c * 64 + p] = val;
    }
    __syncthreads();

    const int wave = cg;                // p == lane within wave

    // ---------------- layer 1: o = wave*64 + og*8 + i ----------------
    float y[64];
    #pragma unroll
    for (int og = 0; og < 8; ++og) {
        const int o0 = wave * 64 + og * 8;
        float acc[8];
        #pragma unroll
        for (int i = 0; i < 8; ++i) acc[i] = 0.0f;

        #pragma unroll 4
        for (int c = 0; c < DD; ++c) {
            float xv = xls[c * 64 + p];
            #pragma unroll
            for (int i = 0; i < 8; ++i)
                acc[i] = fmaf(W1[(size_t)(o0 + i) * DD + c], xv, acc[i]);
        }
        #pragma unroll
        for (int i = 0; i < 8; ++i) {
            const int o = o0 + i;
            float sc  = g1[o] / sqrtf(v1[o] + 1e-5f);
            float val = (acc[i] + b1[o] - m1[o]) * sc + be1[o];
            y[og * 8 + i] = fmaxf(val, 0.0f);
        }
    }

    __syncthreads();                    // all waves done reading x
    #pragma unroll
    for (int i = 0; i < 64; ++i)
        xls[(wave * 64 + i) * 64 + p] = y[i];
    __syncthreads();

    // ---------------- layer 2: o = wave*32 + og*8 + i ----------------
    #pragma unroll
    for (int og = 0; og < 4; ++og) {
        const int o0 = wave * 32 + og * 8;
        float acc[8];
        #pragma unroll
        for (int i = 0; i < 8; ++i) acc[i] = 0.0f;

        #pragma unroll 4
        for (int c = 0; c < O1; ++c) {
            float xv = xls[c * 64 + p];
            #pragma unroll
            for (int i = 0; i < 8; ++i)
                acc[i] = fmaf(W2[(size_t)(o0 + i) * O1 + c], xv, acc[i]);
        }
        #pragma unroll
        for (int i = 0; i < 8; ++i) {
            const int o = o0 + i;
            float sc  = g2[o] / sqrtf(v2[o] + 1e-5f);
            float val = (acc[i] + b2[o] - m2[o]) * sc + be2[o];
            out[((size_t)b * O2 + o) * NN + n] = fmaxf(val, 0.0f);
        }
    }
}

// ---------------------------------------------------------------------------
extern "C" void kernel_launch(void* const* d_in, const int* in_sizes, int n_in,
                              void* d_out, int out_size, void* d_ws, size_t ws_size,
                              hipStream_t stream) {
    const float* xyz1    = (const float*)d_in[0];
    const float* xyz2    = (const float*)d_in[1];
    const float* points1 = (const float*)d_in[2];
    const float* points2 = (const float*)d_in[3];
    const float* W1  = (const float*)d_in[4];
    const float* b1  = (const float*)d_in[5];
    const float* g1  = (const float*)d_in[6];
    const float* be1 = (const float*)d_in[7];
    const float* m1  = (const float*)d_in[8];
    const float* v1  = (const float*)d_in[9];
    const float* W2  = (const float*)d_in[10];
    const float* b2  = (const float*)d_in[11];
    const float* g2  = (const float*)d_in[12];
    const float* be2 = (const float*)d_in[13];
    const float* m2  = (const float*)d_in[14];
    const float* v2  = (const float*)d_in[15];

    float* out = (float*)d_out;

    // workspace: idx [B*N*3] int, then weights [B*N*3] float
    int*   ws_idx = (int*)d_ws;
    float* ws_w   = (float*)((char*)d_ws + (size_t)BB * NN * 3 * sizeof(int));

    dim3 gridA(BB * (NN / 256));
    knn3_kernel<<<gridA, 256, 0, stream>>>(xyz1, xyz2, ws_idx, ws_w);

    dim3 gridB(BB * (NN / 64));
    fused_interp_mlp_kernel<<<gridB, 256, 0, stream>>>(
        points1, points2, ws_idx, ws_w,
        W1, b1, g1, be1, m1, v1,
        W2, b2, g2, be2, m2, v2,
        out);
}

// Round 6
// 268.215 us; speedup vs baseline: 3.9938x; 3.9938x over previous
//
#include <hip/hip_runtime.h>
#include <hip/hip_bf16.h>

#define BB 16
#define NN 4096
#define SS 1024
#define DD 256
#define O1C 256
#define O2C 128
#define NT 128   // n-tile of fused kernel

typedef __attribute__((ext_vector_type(8))) short bf16x8;
typedef __attribute__((ext_vector_type(4))) float f32x4;
typedef __attribute__((ext_vector_type(2))) unsigned int u32x2;

static __device__ __forceinline__ unsigned short f2bf(float f) {
    union { float f; unsigned u; } v; v.f = f;
    unsigned r = (v.u + 0x7fffu + ((v.u >> 16) & 1u)) >> 16;
    return (unsigned short)r;
}

// ---------------------------------------------------------------------------
// Prep: W fp32 -> bf16, fold BN into scale/shift.  grid 384 x 256.
// ---------------------------------------------------------------------------
__global__ __launch_bounds__(256) void prep_kernel(
    const float* __restrict__ W1, const float* __restrict__ W2,
    const float* __restrict__ b1, const float* __restrict__ g1,
    const float* __restrict__ be1, const float* __restrict__ m1,
    const float* __restrict__ v1,
    const float* __restrict__ b2, const float* __restrict__ g2,
    const float* __restrict__ be2, const float* __restrict__ m2,
    const float* __restrict__ v2,
    unsigned short* __restrict__ W1b, unsigned short* __restrict__ W2b,
    float* __restrict__ sc1, float* __restrict__ sh1,
    float* __restrict__ sc2, float* __restrict__ sh2)
{
    int t = blockIdx.x * 256 + threadIdx.x;
    if (t < O1C * DD) W1b[t] = f2bf(W1[t]);
    int t2 = t - O1C * DD;
    if (t2 >= 0 && t2 < O2C * O1C) W2b[t2] = f2bf(W2[t2]);
    if (t < O1C) {
        float s = g1[t] / sqrtf(v1[t] + 1e-5f);
        sc1[t] = s;
        sh1[t] = (b1[t] - m1[t]) * s + be1[t];
    }
    if (t2 >= 0 && t2 < O2C) {
        float s = g2[t2] / sqrtf(v2[t2] + 1e-5f);
        sc2[t2] = s;
        sh2[t2] = (b2[t2] - m2[t2]) * s + be2[t2];
    }
}

// ---------------------------------------------------------------------------
// knn3: 4 threads per point, each scans S/4, stable LDS merge.
// grid: BB * (NN/64) = 1024 blocks x 256 threads.
// ---------------------------------------------------------------------------
__global__ __launch_bounds__(256) void knn3_kernel(
    const float* __restrict__ xyz1,   // [B,3,N]
    const float* __restrict__ xyz2,   // [B,3,S]
    int* __restrict__ idx_out,        // [B,N,3]
    float* __restrict__ w_out)        // [B,N,3]
{
    __shared__ float4 q[SS];          // 16 KB
    __shared__ float  cd[256][3];     // 3 KB
    __shared__ int    ci[256][3];     // 3 KB

    const int b    = blockIdx.x >> 6;     // 64 tiles per batch
    const int tile = blockIdx.x & 63;
    const int p    = threadIdx.x & 63;
    const int seg  = threadIdx.x >> 6;    // 0..3: which quarter of S
    const int n    = tile * 64 + p;

    const float* x2 = xyz2 + (size_t)b * 3 * SS;
    for (int s = threadIdx.x; s < SS; s += 256) {
        float xx = x2[s], yy = x2[SS + s], zz = x2[2 * SS + s];
        q[s] = make_float4(xx, yy, zz, xx * xx + yy * yy + zz * zz);
    }
    __syncthreads();

    const float* x1 = xyz1 + (size_t)b * 3 * NN;
    const float px = x1[n], py = x1[NN + n], pz = x1[2 * NN + n];
    const float pn = px * px + py * py + pz * pz;

    const float FINF = 3.402823466e+38f;
    float d0 = FINF, d1 = FINF, d2 = FINF;
    int   i0 = 0,    i1 = 0,    i2 = 0;

    const int s0 = seg * (SS / 4);
    #pragma unroll 4
    for (int s = s0; s < s0 + SS / 4; ++s) {
        float4 v = q[s];
        float d = pn + v.w - 2.0f * (px * v.x + py * v.y + pz * v.z);
        if (d < d2) {
            if (d < d1) {
                if (d < d0) { d2 = d1; i2 = i1; d1 = d0; i1 = i0; d0 = d; i0 = s; }
                else        { d2 = d1; i2 = i1; d1 = d;  i1 = s; }
            } else          { d2 = d;  i2 = s; }
        }
    }
    cd[threadIdx.x][0] = d0; cd[threadIdx.x][1] = d1; cd[threadIdx.x][2] = d2;
    ci[threadIdx.x][0] = i0; ci[threadIdx.x][1] = i1; ci[threadIdx.x][2] = i2;
    __syncthreads();

    if (threadIdx.x < 64) {
        float m0 = cd[p][0], m1v = cd[p][1], m2v = cd[p][2];
        int   j0 = ci[p][0], j1 = ci[p][1], j2 = ci[p][2];
        #pragma unroll
        for (int qq = 1; qq < 4; ++qq) {
            const int t = qq * 64 + p;
            #pragma unroll
            for (int c = 0; c < 3; ++c) {
                float d = cd[t][c]; int i = ci[t][c];
                // strict < keeps earliest index on ties (top_k stability)
                if (d < m2v) {
                    if (d < m1v) {
                        if (d < m0) { m2v = m1v; j2 = j1; m1v = m0; j1 = j0; m0 = d; j0 = i; }
                        else        { m2v = m1v; j2 = j1; m1v = d;  j1 = i; }
                    } else          { m2v = d;  j2 = i; }
                }
            }
        }
        float r0 = 1.0f / (m0 + 1e-8f);
        float r1 = 1.0f / (m1v + 1e-8f);
        float r2 = 1.0f / (m2v + 1e-8f);
        float rs = 1.0f / (r0 + r1 + r2);
        size_t base = ((size_t)b * NN + n) * 3;
        idx_out[base + 0] = j0;
        idx_out[base + 1] = j1;
        idx_out[base + 2] = j2;
        w_out[base + 0] = r0 * rs;
        w_out[base + 1] = r1 * rs;
        w_out[base + 2] = r2 * rs;
    }
}

// ---------------------------------------------------------------------------
// Fused interp + MFMA MLP.  grid: BB*(NN/NT) = 512 blocks x 512 threads.
// LDS: one 64 KB buffer T holding X^T[128 n][256 k] bf16, then Y^T[128][256].
// Swizzle: byte_in_row ^= (row&7)<<4  (conflict-free b128 both sides).
// GEMM via mfma_f32_16x16x32_bf16: A=W rows (global bf16), B=T (LDS).
// ---------------------------------------------------------------------------
__global__ __launch_bounds__(512) void fused_mfma_kernel(
    const float* __restrict__ points1,  // [B,D,N]
    const float* __restrict__ points2,  // [B,D,S]
    const int*   __restrict__ idx_in,   // [B,N,3]
    const float* __restrict__ w_in,     // [B,N,3]
    const unsigned short* __restrict__ W1b,  // [O1,D] bf16
    const unsigned short* __restrict__ W2b,  // [O2,O1] bf16
    const float* __restrict__ sc1, const float* __restrict__ sh1,
    const float* __restrict__ sc2, const float* __restrict__ sh2,
    float* __restrict__ out)            // [B,O2,N]
{
    __shared__ unsigned short T[NT * DD];   // 64 KB

    const int blk  = blockIdx.x;
    const int b    = blk >> 5;            // 32 tiles per batch
    const int n0   = (blk & 31) * NT;
    const int tid  = threadIdx.x;
    const int lane = tid & 63;
    const int w    = tid >> 6;            // wave 0..7

    // ---------------- stage X^T[p][c] (interp) ----------------
    {
        const int p  = tid & 127;         // point within tile
        const int cg = tid >> 7;          // 0..3 channel group
        const int n  = n0 + p;
        const size_t ibase = ((size_t)b * NN + n) * 3;
        const int   gi0 = idx_in[ibase + 0];
        const int   gi1 = idx_in[ibase + 1];
        const int   gi2 = idx_in[ibase + 2];
        const float gw0 = w_in[ibase + 0];
        const float gw1 = w_in[ibase + 1];
        const float gw2 = w_in[ibase + 2];
        const float* p1 = points1 + (size_t)b * DD * NN + n;
        const float* p2 = points2 + (size_t)b * DD * SS;

        for (int cc = 0; cc < 8; ++cc) {
            const int c0 = (cg * 8 + cc) * 8;     // 8 consecutive channels
            bf16x8 v8;
            #pragma unroll
            for (int k = 0; k < 8; ++k) {
                const int c = c0 + k;
                const float* row = p2 + (size_t)c * SS;
                float val = p1[(size_t)c * NN]
                          + gw0 * row[gi0] + gw1 * row[gi1] + gw2 * row[gi2];
                v8[k] = (short)f2bf(val);
            }
            const int byteoff = p * 512 + ((c0 * 2) ^ ((p & 7) << 4));
            *reinterpret_cast<bf16x8*>(reinterpret_cast<char*>(T) + byteoff) = v8;
        }
    }
    __syncthreads();

    const int r16 = lane & 15;
    const int kg  = lane >> 4;
    const int wo  = w >> 1;               // 0..3
    const int wn  = w & 1;                // 0..1

    // ---------------- GEMM1: [256 o] x [k=256] x [128 n] ----------------
    f32x4 acc[4][4] = {};
    for (int ks = 0; ks < 8; ++ks) {
        const int kk = ks * 32;
        bf16x8 a[4], bf[4];
        #pragma unroll
        for (int m = 0; m < 4; ++m) {
            const int o = wo * 64 + m * 16 + r16;
            a[m] = *reinterpret_cast<const bf16x8*>(W1b + (size_t)o * DD + kk + kg * 8);
        }
        #pragma unroll
        for (int j = 0; j < 4; ++j) {
            const int nn = wn * 64 + j * 16 + r16;
            const int byteoff = nn * 512 + (((kk + kg * 8) * 2) ^ ((nn & 7) << 4));
            bf[j] = *reinterpret_cast<const bf16x8*>(reinterpret_cast<const char*>(T) + byteoff);
        }
        #pragma unroll
        for (int m = 0; m < 4; ++m)
            #pragma unroll
            for (int j = 0; j < 4; ++j)
                acc[m][j] = __builtin_amdgcn_mfma_f32_16x16x32_bf16(a[m], bf[j], acc[m][j], 0, 0, 0);
    }
    __syncthreads();    // everyone done reading X^T

    // epilogue 1: BN + ReLU -> bf16 -> Y^T[n][o] (same LDS buffer)
    #pragma unroll
    for (int m = 0; m < 4; ++m) {
        const int o0 = wo * 64 + m * 16 + kg * 4;
        const float4 s4 = *reinterpret_cast<const float4*>(sc1 + o0);
        const float4 h4 = *reinterpret_cast<const float4*>(sh1 + o0);
        #pragma unroll
        for (int j = 0; j < 4; ++j) {
            const int nn = wn * 64 + j * 16 + r16;
            float v0 = fmaxf(acc[m][j][0] * s4.x + h4.x, 0.0f);
            float v1 = fmaxf(acc[m][j][1] * s4.y + h4.y, 0.0f);
            float v2 = fmaxf(acc[m][j][2] * s4.z + h4.z, 0.0f);
            float v3 = fmaxf(acc[m][j][3] * s4.w + h4.w, 0.0f);
            u32x2 pk;
            pk[0] = (unsigned)f2bf(v0) | ((unsigned)f2bf(v1) << 16);
            pk[1] = (unsigned)f2bf(v2) | ((unsigned)f2bf(v3) << 16);
            const int byteoff = nn * 512 + ((o0 * 2) ^ ((nn & 7) << 4));
            *reinterpret_cast<u32x2*>(reinterpret_cast<char*>(T) + byteoff) = pk;
        }
    }
    __syncthreads();

    // ---------------- GEMM2: [128 o2] x [k=256] x [128 n] ----------------
    f32x4 acc2[2][4] = {};
    for (int ks = 0; ks < 8; ++ks) {
        const int kk = ks * 32;
        bf16x8 a[2], bf[4];
        #pragma unroll
        for (int m = 0; m < 2; ++m) {
            const int o = wo * 32 + m * 16 + r16;
            a[m] = *reinterpret_cast<const bf16x8*>(W2b + (size_t)o * O1C + kk + kg * 8);
        }
        #pragma unroll
        for (int j = 0; j < 4; ++j) {
            const int nn = wn * 64 + j * 16 + r16;
            const int byteoff = nn * 512 + (((kk + kg * 8) * 2) ^ ((nn & 7) << 4));
            bf[j] = *reinterpret_cast<const bf16x8*>(reinterpret_cast<const char*>(T) + byteoff);
        }
        #pragma unroll
        for (int m = 0; m < 2; ++m)
            #pragma unroll
            for (int j = 0; j < 4; ++j)
                acc2[m][j] = __builtin_amdgcn_mfma_f32_16x16x32_bf16(a[m], bf[j], acc2[m][j], 0, 0, 0);
    }

    // epilogue 2: BN + ReLU -> fp32 global store
    #pragma unroll
    for (int m = 0; m < 2; ++m) {
        const int o0 = wo * 32 + m * 16 + kg * 4;
        const float4 s4 = *reinterpret_cast<const float4*>(sc2 + o0);
        const float4 h4 = *reinterpret_cast<const float4*>(sh2 + o0);
        #pragma unroll
        for (int j = 0; j < 4; ++j) {
            const int nn = wn * 64 + j * 16 + r16;
            const size_t obase = ((size_t)b * O2C + o0) * NN + n0 + nn;
            out[obase]            = fmaxf(acc2[m][j][0] * s4.x + h4.x, 0.0f);
            out[obase + NN]       = fmaxf(acc2[m][j][1] * s4.y + h4.y, 0.0f);
            out[obase + 2 * NN]   = fmaxf(acc2[m][j][2] * s4.z + h4.z, 0.0f);
            out[obase + 3 * NN]   = fmaxf(acc2[m][j][3] * s4.w + h4.w, 0.0f);
        }
    }
}

// ---------------------------------------------------------------------------
extern "C" void kernel_launch(void* const* d_in, const int* in_sizes, int n_in,
                              void* d_out, int out_size, void* d_ws, size_t ws_size,
                              hipStream_t stream) {
    const float* xyz1    = (const float*)d_in[0];
    const float* xyz2    = (const float*)d_in[1];
    const float* points1 = (const float*)d_in[2];
    const float* points2 = (const float*)d_in[3];
    const float* W1  = (const float*)d_in[4];
    const float* b1  = (const float*)d_in[5];
    const float* g1  = (const float*)d_in[6];
    const float* be1 = (const float*)d_in[7];
    const float* m1  = (const float*)d_in[8];
    const float* v1  = (const float*)d_in[9];
    const float* W2  = (const float*)d_in[10];
    const float* b2  = (const float*)d_in[11];
    const float* g2  = (const float*)d_in[12];
    const float* be2 = (const float*)d_in[13];
    const float* m2  = (const float*)d_in[14];
    const float* v2  = (const float*)d_in[15];

    float* out = (float*)d_out;

    // workspace layout
    char* ws = (char*)d_ws;
    int*            ws_idx = (int*)ws;                                   // 786432 B
    float*          ws_w   = (float*)(ws + 786432);                      // 786432 B
    unsigned short* W1b    = (unsigned short*)(ws + 1572864);            // 131072 B
    unsigned short* W2b    = (unsigned short*)(ws + 1703936);            //  65536 B
    float*          sc1    = (float*)(ws + 1769472);                     //   1024 B
    float*          sh1    = (float*)(ws + 1770496);
    float*          sc2    = (float*)(ws + 1771520);                     //    512 B
    float*          sh2    = (float*)(ws + 1772032);

    prep_kernel<<<dim3(384), dim3(256), 0, stream>>>(
        W1, W2, b1, g1, be1, m1, v1, b2, g2, be2, m2, v2,
        W1b, W2b, sc1, sh1, sc2, sh2);

    knn3_kernel<<<dim3(BB * (NN / 64)), dim3(256), 0, stream>>>(
        xyz1, xyz2, ws_idx, ws_w);

    fused_mfma_kernel<<<dim3(BB * (NN / NT)), dim3(512), 0, stream>>>(
        points1, points2, ws_idx, ws_w,
        W1b, W2b, sc1, sh1, sc2, sh2, out);
}